// Round 8
// baseline (191.250 us; speedup 1.0000x reference)
//
#include <hip/hip_runtime.h>

// Problem constants (match reference)
#define B_ 4
#define N_ 16384
#define M_ 128
#define C_ 128
#define S_ 512
#define ROW_ 131           // 3 + C floats per pooled row
#define NCHUNK_ 256        // 64-point chunks per box (N_/64)
#define TILE_ 128          // unique rows staged in LDS per box
#define LSTR_ 136          // swizzled LDS row stride (floats)
#define KBOX_ 4            // boxes per wave in mask kernel
#define NF4_ ((S_ * ROW_) / 4)   // 16768 float4s per box
#define HF4_ (NF4_ / 2)          // 8384 float4s per half

typedef float f4_t __attribute__((ext_vector_type(4)));

// Swizzled LDS address: for a fixed element-within-float4 slot, consecutive
// lanes (col += 4) land on consecutive banks -> conflict-free ds_read_b32.
// Injective for col in [0,131): (col&3)*34 + (col>>2) <= 3*34+32 = 134 < 136.
__device__ __forceinline__ int swz(int j, int col) {
    return j * LSTR_ + (col & 3) * 34 + (col >> 2);
}

// ---------------------------------------------------------------------------
// Phase A: per-(box, chunk) in-box bitmask via wave ballot.
// One wave holds 16 chunks (1024 points, 48 VGPRs) and tests them against
// KBOX_ consecutive boxes — points read once per 4 boxes. 2048 waves total.
// (R6 lesson: fusing this into the per-box block forfeits the reuse: +18 µs.)
// ---------------------------------------------------------------------------
__global__ __launch_bounds__(256) void mask_kernel(
    const float* __restrict__ points,        // (B, N, 3)
    const float* __restrict__ boxes,         // (B*M, 7)
    unsigned long long* __restrict__ masks,  // (B*M, NCHUNK_)
    int* __restrict__ cnts)                  // (B*M, NCHUNK_)
{
    const int gwave = blockIdx.x * 4 + (threadIdx.x >> 6);
    const int lane  = threadIdx.x & 63;
    const int grp   = gwave >> 4;            // box-group [0, B*M/KBOX_)
    const int seg   = gwave & 15;            // 16 chunks per segment
    const int bm0   = grp * KBOX_;
    const int b     = bm0 >> 7;              // batch (shared by the 4 boxes)

    const float* pb = points + (size_t)b * N_ * 3;
    float px[16], py[16], pz[16];
    #pragma unroll
    for (int k = 0; k < 16; ++k) {
        const int i = (seg * 16 + k) * 64 + lane;
        px[k] = pb[i*3+0]; py[k] = pb[i*3+1]; pz[k] = pb[i*3+2];
    }

    for (int kb = 0; kb < KBOX_; ++kb) {
        const int bm = bm0 + kb;
        const float* bx = boxes + bm * 7;
        const float cx = bx[0], cy = bx[1], czb = bx[2];
        const float dx = bx[3], dy = bx[4], dzv = bx[5], rz = bx[6];
        // fp32 reference semantics: no FMA contraction; trig via double->fp32
        const float cz   = __fadd_rn(czb, __fmul_rn(0.5f, dzv));
        const float cosa = (float)cos(-(double)rz);
        const float sina = (float)sin(-(double)rz);
        const float hdx = 0.5f * dx, hdy = 0.5f * dy, hdz = 0.5f * dzv;

        #pragma unroll
        for (int k = 0; k < 16; ++k) {
            const float sx = __fsub_rn(px[k], cx);
            const float sy = __fsub_rn(py[k], cy);
            const float lx = __fsub_rn(__fmul_rn(sx, cosa), __fmul_rn(sy, sina));
            const float ly = __fadd_rn(__fmul_rn(sx, sina), __fmul_rn(sy, cosa));
            const bool pred = (fabsf(__fsub_rn(pz[k], cz)) <= hdz) &&
                              (lx > -hdx) && (lx < hdx) &&
                              (ly > -hdy) && (ly < hdy);
            const unsigned long long m = __ballot(pred);
            if (lane == 0) {
                const int chunk = seg * 16 + k;
                masks[(size_t)bm * NCHUNK_ + chunk] = m;
                cnts [(size_t)bm * NCHUNK_ + chunk] = __popcll(m);
            }
        }
    }
}

// ---------------------------------------------------------------------------
// Resolve + pool, split-S: TWO blocks per box (grid 1024). Block x handles
// box x>>1, output half x&1. With 4 blocks/CU (2 resident, 74 KB LDS each)
// the ~3 µs prologue (scan/expand/stage) of later blocks hides under earlier
// blocks' NT-store write streams, and tail granularity halves. Prologue work
// is duplicated per half (~15 KB extra L2 reads/box — noise).
// ---------------------------------------------------------------------------
__global__ __launch_bounds__(256) void pool_kernel(
    const float* __restrict__ points,        // (B, N, 3)
    const float* __restrict__ feats,         // (B, N, C)
    const unsigned long long* __restrict__ masks,
    const int* __restrict__ cnts,
    float* __restrict__ out,                 // (B, M, S, 131)
    float* __restrict__ flags_out)           // (B*M,)
{
    const int bm   = blockIdx.x >> 1;
    const int half = blockIdx.x & 1;
    const int b    = bm >> 7;
    const int tid  = threadIdx.x;
    const int w    = tid >> 6;
    const int lane = tid & 63;

    __shared__ int   s_wsum[4];
    __shared__ int   s_idx[S_];
    __shared__ int   jtab[S_ + 1];           // +1: streaming reads jtab[s0+1]
    __shared__ float srow[TILE_ * LSTR_];

    // --- scan chunk counts: wave shuffle-scan + 1 barrier ---
    const int c = cnts[(size_t)bm * NCHUNK_ + tid];
    int incl = c;
    #pragma unroll
    for (int d = 1; d < 64; d <<= 1) {
        const int t = __shfl_up(incl, d, 64);
        if (lane >= d) incl += t;
    }
    if (lane == 63) s_wsum[w] = incl;
    __syncthreads();
    const int w0 = s_wsum[0], w1 = s_wsum[1], w2 = s_wsum[2], w3 = s_wsum[3];
    const int woff  = (w > 0 ? w0 : 0) + (w > 1 ? w1 : 0) + (w > 2 ? w2 : 0);
    const int total = w0 + w1 + w2 + w3;
    const int P = incl - c + woff;           // exclusive prefix (ordered)

    // --- expand ordered in-box indices ---
    if (c > 0 && P < S_) {
        unsigned long long m = masks[(size_t)bm * NCHUNK_ + tid];
        int pos = P;
        while (m && pos < S_) {
            const int bit = __ffsll((unsigned long long)m) - 1;
            m &= m - 1;
            s_idx[pos++] = tid * 64 + bit;
        }
    }
    __syncthreads();

    // --- wrap-around table ---
    const int cnt_eff = total < S_ ? total : S_;
    const int denom   = cnt_eff > 0 ? cnt_eff : 1;
    for (int s = tid; s <= S_; s += 256) jtab[s] = (s < S_) ? (s % denom) : 0;

    // --- stage unique rows into swizzled LDS ---
    const int T = cnt_eff < TILE_ ? cnt_eff : TILE_;
    if (total == 0) {
        if (tid < LSTR_) srow[tid] = 0.0f;   // row 0 zeros (j is always 0)
    } else {
        const int nf4 = T * 32;              // 32 float4s of features per row
        for (int t = tid; t < nf4; t += 256) {
            const int u = t >> 5, q = t & 31;
            const size_t pbase = (size_t)b * N_ + (unsigned)s_idx[u];
            const f4_t v = *(const f4_t*)(feats + pbase * C_ + q * 4);
            #pragma unroll
            for (int jj = 0; jj < 4; ++jj)
                srow[swz(u, 3 + 4 * q + jj)] = v[jj];   // <=2-way: free
        }
        for (int t = tid; t < T * 3; t += 256) {
            const int u = t / 3, k = t - u * 3;
            const size_t pbase = (size_t)b * N_ + (unsigned)s_idx[u];
            srow[swz(u, k)] = points[pbase * 3 + k];
        }
    }
    __syncthreads();

    // --- stream this half: 8384 aligned float4s ---
    float* ob = out + (size_t)bm * (S_ * ROW_);
    const int fend = (half + 1) * HF4_;
    if (cnt_eff <= TILE_) {
        // block-uniform fast path: every referenced row is staged
        for (int f = half * HF4_ + tid; f < fend; f += 256) {
            const int e = 4 * f;
            const unsigned s0 = (unsigned)e / (unsigned)ROW_;  // magic-mul
            const int col0 = e - (int)s0 * ROW_;
            const int ja = jtab[s0], jb = jtab[s0 + 1];
            f4_t v;
            #pragma unroll
            for (int jj = 0; jj < 4; ++jj) {
                int col = col0 + jj;
                const bool cross = col >= ROW_;
                col = cross ? col - ROW_ : col;
                const int j = cross ? jb : ja;
                v[jj] = srow[swz(j, col)];   // stride-1 banks: conflict-free
            }
            __builtin_nontemporal_store(v, (f4_t*)(ob + e));
        }
    } else {
        // rare path: some rows not staged -> per-element fallback to global
        for (int f = half * HF4_ + tid; f < fend; f += 256) {
            const int e = 4 * f;
            const unsigned s0 = (unsigned)e / (unsigned)ROW_;
            const int col0 = e - (int)s0 * ROW_;
            f4_t v;
            #pragma unroll
            for (int jj = 0; jj < 4; ++jj) {
                int col = col0 + jj;
                unsigned s = s0;
                if (col >= ROW_) { col -= ROW_; ++s; }
                const int j = jtab[s];
                float val;
                if (j < TILE_) {
                    val = srow[swz(j, col)];
                } else {
                    const size_t pbase = (size_t)b * N_ + (unsigned)s_idx[j];
                    val = (col < 3) ? points[pbase * 3 + col]
                                    : feats[pbase * C_ + (col - 3)];
                }
                v[jj] = val;
            }
            __builtin_nontemporal_store(v, (f4_t*)(ob + e));
        }
    }
    if (tid == 0 && half == 0) flags_out[bm] = (total == 0) ? 1.0f : 0.0f;
}

extern "C" void kernel_launch(void* const* d_in, const int* in_sizes, int n_in,
                              void* d_out, int out_size, void* d_ws, size_t ws_size,
                              hipStream_t stream) {
    const float* points = (const float*)d_in[0];   // (B, N, 3)
    const float* feats  = (const float*)d_in[1];   // (B, N, C)
    const float* boxes  = (const float*)d_in[2];   // (B, M, 7)
    float* out = (float*)d_out;

    // Workspace: masks (1 MB) + cnts (0.5 MB)
    unsigned long long* masks = (unsigned long long*)d_ws;
    int* cnts = (int*)((char*)d_ws + (size_t)B_ * M_ * NCHUNK_ * 8);

    float* flags = out + (size_t)B_ * M_ * S_ * ROW_;

    // Phase A: (512/KBOX_) box-groups x 16 segments = 2048 waves = 512 blocks
    mask_kernel<<<B_ * M_ * 16 / 4 / KBOX_, 256, 0, stream>>>(
        points, boxes, masks, cnts);
    // Resolve + pool: two blocks per box (split-S)
    pool_kernel<<<B_ * M_ * 2, 256, 0, stream>>>(points, feats, masks, cnts, out, flags);
}

// Round 9
// 180.657 us; speedup vs baseline: 1.0586x; 1.0586x over previous
//
#include <hip/hip_runtime.h>

// Problem constants (match reference)
#define B_ 4
#define N_ 16384
#define M_ 128
#define C_ 128
#define S_ 512
#define ROW_ 131           // 3 + C floats per pooled row
#define NCHUNK_ 256        // 64-point chunks per box (N_/64)
#define TILE_ 128          // unique rows staged in LDS per box
#define LSTR_ 136          // swizzled LDS row stride (floats)
#define KBOX_ 4            // boxes per wave in mask kernel

typedef float f4_t __attribute__((ext_vector_type(4)));

// Swizzled LDS address: for a fixed element-within-float4 slot, consecutive
// lanes (col += 4) land on consecutive banks -> conflict-free ds_read_b32.
// Injective for col in [0,131): (col&3)*34 + (col>>2) <= 3*34+32 = 134 < 136.
__device__ __forceinline__ int swz(int j, int col) {
    return j * LSTR_ + (col & 3) * 34 + (col >> 2);
}

// ---------------------------------------------------------------------------
// Phase A: per-(box, chunk) in-box bitmask via wave ballot.
// One wave holds 16 chunks (1024 points, 48 VGPRs) and tests them against
// KBOX_ consecutive boxes — points read once per 4 boxes. 2048 waves total.
// (R6 lesson: fusing into the per-box block forfeits the reuse: +18 µs.
//  R8 lesson: split-S duplicates the pool prologue for zero overlap: +7 µs.)
// ---------------------------------------------------------------------------
__global__ __launch_bounds__(256) void mask_kernel(
    const float* __restrict__ points,        // (B, N, 3)
    const float* __restrict__ boxes,         // (B*M, 7)
    unsigned long long* __restrict__ masks)  // (B*M, NCHUNK_)
{
    const int gwave = blockIdx.x * 4 + (threadIdx.x >> 6);
    const int lane  = threadIdx.x & 63;
    const int grp   = gwave >> 4;            // box-group [0, B*M/KBOX_)
    const int seg   = gwave & 15;            // 16 chunks per segment
    const int bm0   = grp * KBOX_;
    const int b     = bm0 >> 7;              // batch (shared by the 4 boxes)

    const float* pb = points + (size_t)b * N_ * 3;
    float px[16], py[16], pz[16];
    #pragma unroll
    for (int k = 0; k < 16; ++k) {
        const int i = (seg * 16 + k) * 64 + lane;
        px[k] = pb[i*3+0]; py[k] = pb[i*3+1]; pz[k] = pb[i*3+2];
    }

    for (int kb = 0; kb < KBOX_; ++kb) {
        const int bm = bm0 + kb;
        const float* bx = boxes + bm * 7;
        const float cx = bx[0], cy = bx[1], czb = bx[2];
        const float dx = bx[3], dy = bx[4], dzv = bx[5], rz = bx[6];
        // fp32 reference semantics: no FMA contraction; trig via double->fp32
        const float cz   = __fadd_rn(czb, __fmul_rn(0.5f, dzv));
        const float cosa = (float)cos(-(double)rz);
        const float sina = (float)sin(-(double)rz);
        const float hdx = 0.5f * dx, hdy = 0.5f * dy, hdz = 0.5f * dzv;

        #pragma unroll
        for (int k = 0; k < 16; ++k) {
            const float sx = __fsub_rn(px[k], cx);
            const float sy = __fsub_rn(py[k], cy);
            const float lx = __fsub_rn(__fmul_rn(sx, cosa), __fmul_rn(sy, sina));
            const float ly = __fadd_rn(__fmul_rn(sx, sina), __fmul_rn(sy, cosa));
            const bool pred = (fabsf(__fsub_rn(pz[k], cz)) <= hdz) &&
                              (lx > -hdx) && (lx < hdx) &&
                              (ly > -hdy) && (ly < hdy);
            const unsigned long long m = __ballot(pred);
            if (lane == 0) masks[(size_t)bm * NCHUNK_ + seg * 16 + k] = m;
        }
    }
}

// ---------------------------------------------------------------------------
// Resolve + pool: one block per box (R7 structure — the proven shape).
// Load mask word (single dependent L2 read) -> popcount -> shuffle-scan
// (1 barrier) -> expand first min(cnt,S) ordered indices from the
// register-resident mask -> jtab[s]=s%cnt -> stage up to TILE_ rows in
// swizzled LDS -> stream 512x131 floats as NT float4 pure write stream.
// ---------------------------------------------------------------------------
__global__ __launch_bounds__(256) void pool_kernel(
    const float* __restrict__ points,        // (B, N, 3)
    const float* __restrict__ feats,         // (B, N, C)
    const unsigned long long* __restrict__ masks,
    float* __restrict__ out,                 // (B, M, S, 131)
    float* __restrict__ flags_out)           // (B*M,)
{
    const int bm   = blockIdx.x;
    const int b    = bm >> 7;
    const int tid  = threadIdx.x;
    const int w    = tid >> 6;
    const int lane = tid & 63;

    __shared__ int   s_wsum[4];
    __shared__ int   s_idx[S_];
    __shared__ int   jtab[S_ + 1];           // +1: streaming reads jtab[s0+1]
    __shared__ float srow[TILE_ * LSTR_];

    // --- single dependent global read; everything else derives from it ---
    const unsigned long long m0 = masks[(size_t)bm * NCHUNK_ + tid];
    const int c = __popcll(m0);

    // --- scan chunk counts: wave shuffle-scan + 1 barrier ---
    int incl = c;
    #pragma unroll
    for (int d = 1; d < 64; d <<= 1) {
        const int t = __shfl_up(incl, d, 64);
        if (lane >= d) incl += t;
    }
    if (lane == 63) s_wsum[w] = incl;
    __syncthreads();
    const int w0 = s_wsum[0], w1 = s_wsum[1], w2 = s_wsum[2], w3 = s_wsum[3];
    const int woff  = (w > 0 ? w0 : 0) + (w > 1 ? w1 : 0) + (w > 2 ? w2 : 0);
    const int total = w0 + w1 + w2 + w3;
    const int P = incl - c + woff;           // exclusive prefix (ordered)

    // --- expand ordered in-box indices (mask already in register) ---
    if (c > 0 && P < S_) {
        unsigned long long m = m0;
        int pos = P;
        while (m && pos < S_) {
            const int bit = __ffsll((unsigned long long)m) - 1;
            m &= m - 1;
            s_idx[pos++] = tid * 64 + bit;
        }
    }
    __syncthreads();

    // --- wrap-around table ---
    const int cnt_eff = total < S_ ? total : S_;
    const int denom   = cnt_eff > 0 ? cnt_eff : 1;
    for (int s = tid; s <= S_; s += 256) jtab[s] = (s < S_) ? (s % denom) : 0;

    // --- stage unique rows into swizzled LDS ---
    const int T = cnt_eff < TILE_ ? cnt_eff : TILE_;
    if (total == 0) {
        if (tid < LSTR_) srow[tid] = 0.0f;   // row 0 zeros (j is always 0)
    } else {
        const int nf4 = T * 32;              // 32 float4s of features per row
        for (int t = tid; t < nf4; t += 256) {
            const int u = t >> 5, q = t & 31;
            const size_t pbase = (size_t)b * N_ + (unsigned)s_idx[u];
            const f4_t v = *(const f4_t*)(feats + pbase * C_ + q * 4);
            #pragma unroll
            for (int jj = 0; jj < 4; ++jj)
                srow[swz(u, 3 + 4 * q + jj)] = v[jj];   // <=2-way: free
        }
        for (int t = tid; t < T * 3; t += 256) {
            const int u = t / 3, k = t - u * 3;
            const size_t pbase = (size_t)b * N_ + (unsigned)s_idx[u];
            srow[swz(u, k)] = points[pbase * 3 + k];
        }
    }
    __syncthreads();

    // --- stream output: 512*131 = 67072 floats = 16768 aligned float4s ---
    float* ob = out + (size_t)bm * (S_ * ROW_);
    if (cnt_eff <= TILE_) {
        // block-uniform fast path: every referenced row is staged
        for (int f = tid; f < (S_ * ROW_) / 4; f += 256) {
            const int e = 4 * f;
            const unsigned s0 = (unsigned)e / (unsigned)ROW_;  // magic-mul
            const int col0 = e - (int)s0 * ROW_;
            const int ja = jtab[s0], jb = jtab[s0 + 1];
            f4_t v;
            #pragma unroll
            for (int jj = 0; jj < 4; ++jj) {
                int col = col0 + jj;
                const bool cross = col >= ROW_;
                col = cross ? col - ROW_ : col;
                const int j = cross ? jb : ja;
                v[jj] = srow[swz(j, col)];   // stride-1 banks: conflict-free
            }
            __builtin_nontemporal_store(v, (f4_t*)(ob + e));
        }
    } else {
        // rare path: some rows not staged -> per-element fallback to global
        for (int f = tid; f < (S_ * ROW_) / 4; f += 256) {
            const int e = 4 * f;
            const unsigned s0 = (unsigned)e / (unsigned)ROW_;
            const int col0 = e - (int)s0 * ROW_;
            f4_t v;
            #pragma unroll
            for (int jj = 0; jj < 4; ++jj) {
                int col = col0 + jj;
                unsigned s = s0;
                if (col >= ROW_) { col -= ROW_; ++s; }
                const int j = jtab[s];
                float val;
                if (j < TILE_) {
                    val = srow[swz(j, col)];
                } else {
                    const size_t pbase = (size_t)b * N_ + (unsigned)s_idx[j];
                    val = (col < 3) ? points[pbase * 3 + col]
                                    : feats[pbase * C_ + (col - 3)];
                }
                v[jj] = val;
            }
            __builtin_nontemporal_store(v, (f4_t*)(ob + e));
        }
    }
    if (tid == 0) flags_out[bm] = (total == 0) ? 1.0f : 0.0f;
}

extern "C" void kernel_launch(void* const* d_in, const int* in_sizes, int n_in,
                              void* d_out, int out_size, void* d_ws, size_t ws_size,
                              hipStream_t stream) {
    const float* points = (const float*)d_in[0];   // (B, N, 3)
    const float* feats  = (const float*)d_in[1];   // (B, N, C)
    const float* boxes  = (const float*)d_in[2];   // (B, M, 7)
    float* out = (float*)d_out;

    // Workspace: masks (1 MB)
    unsigned long long* masks = (unsigned long long*)d_ws;

    float* flags = out + (size_t)B_ * M_ * S_ * ROW_;

    // Phase A: (512/KBOX_) box-groups x 16 segments = 2048 waves = 512 blocks
    mask_kernel<<<B_ * M_ * 16 / 4 / KBOX_, 256, 0, stream>>>(
        points, boxes, masks);
    // Resolve + pool: one block per box
    pool_kernel<<<B_ * M_, 256, 0, stream>>>(points, feats, masks, out, flags);
}